// Round 11
// baseline (35.073 us; speedup 1.0000x reference)
//
#include <hip/hip_runtime.h>

#define N1    2001
#define EMB   64
#define NSHOW 5
#define MSONG 25
#define NPOS  (NSHOW * MSONG)   // 125
#define MAXU  128
#define NT    1024
#define WT    68                // transposed-weight row stride

__global__ __launch_bounds__(NT)
__attribute__((amdgpu_waves_per_eu(4, 4)))
void setsgnn_kernel(
    const int* __restrict__ song_ids,
    const int* __restrict__ prev_setlists,
    const int* __restrict__ venue_ids,
    const int* __restrict__ tour_ids,
    const int* __restrict__ country_ids,
    const int* __restrict__ is_festival,
    const int* __restrict__ is_marathon,
    const float* __restrict__ song_emb,
    const float* __restrict__ gcn_w1, const float* __restrict__ gcn_b1,
    const float* __restrict__ gcn_w2, const float* __restrict__ gcn_b2,
    const float* __restrict__ q_w,  const float* __restrict__ q_b,
    const float* __restrict__ k_w,  const float* __restrict__ k_b,
    const float* __restrict__ v_w,  const float* __restrict__ v_b,
    const float* __restrict__ venue_t, const float* __restrict__ tour_t,
    const float* __restrict__ country_t, const float* __restrict__ fest_t,
    const float* __restrict__ mara_t,
    const float* __restrict__ ctx_w, const float* __restrict__ ctx_b,
    const float* __restrict__ p1_w,  const float* __restrict__ p1_b,
    const float* __restrict__ p2_w,  const float* __restrict__ p2_b,
    const float* __restrict__ p3_w,  const float* __restrict__ p3_b,
    float* __restrict__ out)
{
    const int b    = blockIdx.x;
    const int tid  = threadIdx.x;
    const int wv   = tid >> 6;
    const int lane = tid & 63;
    const int col0 = tid & 63;      // weight-staging column
    const int eq0  = tid >> 6;      // weight-staging e-quad

    __shared__ __align__(16) float xb0[MAXU][EMB];     // GCN state, in-place
    __shared__ __align__(16) float ybuf[MAXU][EMB];    // per-row x@W products
    __shared__ __align__(16) float wldsT[2][EMB][WT];  // w1,w2 transposed; later k,v
    __shared__ __align__(16) float ctxw_l[56][EMB];
    __shared__ __align__(16) float qw_l[EMB][EMB];
    __shared__ __align__(16) float blds[2][EMB];
    __shared__ __align__(16) float bias_ctx[EMB], bias_q[EMB], bias_k[EMB], bias_v[EMB];
    __shared__ __align__(16) float bias_p1[128], bias_p2[EMB], bias_p3w[EMB];
    __shared__ float bias_p3b;
    __shared__ unsigned short idmap[N1];
    __shared__ int   sl[NPOS];
    __shared__ int   pmap[NPOS];
    __shared__ int   list_ids[MAXU];
    __shared__ float c_us[MAXU][NSHOW];
    __shared__ float occv[MAXU];
    __shared__ float invv[MAXU];
    __shared__ float cntm1[NSHOW];
    __shared__ float invc[NSHOW];
    __shared__ int   U_cnt;
    __shared__ __align__(16) float Xsum[NSHOW][EMB];   // show sums (post-GCN)
    __shared__ float XW[NSHOW][EMB];
    __shared__ float ctxin[56];
    __shared__ float ctxv[EMB];
    __shared__ float qv[EMB];
    __shared__ float vatt[NSHOW][EMB];
    __shared__ float attnw[NSHOW];
    __shared__ float h1b[128];
    __shared__ float partial[NT];

    // ======== P0: ALL early global loads; init; stage to LDS ========
    float w1r[4], w2r[4];
    #pragma unroll
    for (int j = 0; j < 4; j++) w1r[j] = gcn_w1[(eq0 * 4 + j) * EMB + col0];
    #pragma unroll
    for (int j = 0; j < 4; j++) w2r[j] = gcn_w2[(eq0 * 4 + j) * EMB + col0];
    const float4 qw4 = ((const float4*)q_w)[tid];
    float4 cw4 = make_float4(0.f, 0.f, 0.f, 0.f);
    if (tid < 896) cw4 = ((const float4*)ctx_w)[tid];
    float4 bb;
    if (tid < 32) bb = (tid < 16) ? ((const float4*)gcn_b1)[tid]
                                  : ((const float4*)gcn_b2)[tid - 16];
    const int slr = (tid < NPOS) ? prev_setlists[b * NPOS + tid] : 0;
    const int sid    = song_ids[b];
    const int vid    = venue_ids[b];
    const int tourid = tour_ids[b];
    const int cid    = country_ids[b];
    const int fid    = is_festival[b];
    const int mid    = is_marathon[b];

    for (int i = tid; i < N1; i += NT) idmap[i] = 0xFFFFu;
    if (tid < MAXU * NSHOW) ((float*)c_us)[tid] = 0.f;
    if (tid < NPOS) sl[tid] = slr;
    if (tid == 0) U_cnt = 0;
    *(float4*)&wldsT[0][col0][eq0 * 4] = make_float4(w1r[0], w1r[1], w1r[2], w1r[3]);
    *(float4*)&wldsT[1][col0][eq0 * 4] = make_float4(w2r[0], w2r[1], w2r[2], w2r[3]);
    ((float4*)qw_l)[tid] = qw4;
    if (tid < 896) ((float4*)ctxw_l)[tid] = cw4;
    if (tid < 32) ((float4*)blds)[tid] = bb;
    {
        int r = tid - 256;
        if (r >= 0 && r < 16)        ((float4*)bias_ctx)[r]       = ((const float4*)ctx_b)[r];
        else if (r >= 16 && r < 32)  ((float4*)bias_q)[r - 16]    = ((const float4*)q_b)[r - 16];
        else if (r >= 32 && r < 48)  ((float4*)bias_k)[r - 32]    = ((const float4*)k_b)[r - 32];
        else if (r >= 48 && r < 64)  ((float4*)bias_v)[r - 48]    = ((const float4*)v_b)[r - 48];
        else if (r >= 64 && r < 96)  ((float4*)bias_p1)[r - 64]   = ((const float4*)p1_b)[r - 64];
        else if (r >= 96 && r < 112) ((float4*)bias_p2)[r - 96]   = ((const float4*)p2_b)[r - 96];
        else if (r >= 112 && r < 128)((float4*)bias_p3w)[r - 112] = ((const float4*)p3_w)[r - 112];
        else if (r == 128)           bias_p3b = p3_b[0];
    }
    __syncthreads();   // B1

    // ======== P1: mark ids | cnt_show | ctxin embed gathers ========
    if (tid < NPOS) { int id = sl[tid]; if (id > 0) idmap[id] = 1u; }
    if (tid == NPOS) idmap[sid] = 1u;
    if (tid >= 128 && tid < 128 + NSHOW) {
        int s = tid - 128, c = 0;
        for (int i = 0; i < MSONG; i++) c += (sl[s * MSONG + i] > 0) ? 1 : 0;
        cntm1[s] = (float)(c - 1);
        invc[s] = 1.f / fmaxf((float)c, 1.f);
    }
    if (tid >= 144 && tid < 200) {
        int e = tid - 144; float val;
        if (e < 16)      val = venue_t[vid * 16 + e];
        else if (e < 32) val = tour_t[tourid * 16 + (e - 16)];
        else if (e < 40) val = country_t[cid * 8 + (e - 32)];
        else if (e < 48) val = fest_t[fid * 8 + (e - 40)];
        else             val = mara_t[mid * 8 + (e - 48)];
        ctxin[e] = val;
    }
    __syncthreads();   // B2

    // ======== P2: ballot compaction | ctx matmul ========
    for (int i = tid; i < N1; i += NT) {
        const bool p = (idmap[i] == 1u);
        const unsigned long long m = __ballot(p);
        int base = 0;
        if (lane == 0) { int c = __popcll(m); if (c) base = atomicAdd(&U_cnt, c); }
        base = __shfl(base, 0, 64);
        if (p) {
            int r = __popcll(m & ((1ull << lane) - 1ull));
            int u = base + r;
            idmap[i] = (unsigned short)u;
            list_ids[u] = i;
        }
    }
    if (tid >= 896 && tid < 960) {
        int c = tid - 896;
        float acc = bias_ctx[c];
        #pragma unroll
        for (int e = 0; e < 56; e++) acc += ctxin[e] * ctxw_l[e][c];
        ctxv[c] = acc;
    }
    __syncthreads();   // B3
    const int U = U_cnt;   // <= 126

    // per-row product: y[uu] = xb0[own row uu] @ W   (own rows only -> in-wave safe)
    #define Y_COMPUTE(L)                                                         \
    {                                                                            \
        _Pragma("unroll")                                                        \
        for (int uu = 0; uu < 8; ++uu) y[uu] = 0.f;                              \
        _Pragma("unroll 4")                                                      \
        for (int e4 = 0; e4 < 16; ++e4) {                                        \
            float4 a[8];                                                         \
            _Pragma("unroll")                                                    \
            for (int uu = 0; uu < 8; ++uu)                                       \
                a[uu] = *(const float4*)&xb0[(uu << 4) | wv][e4 * 4];            \
            const float4 w4 = *(const float4*)&wldsT[L][lane][e4 * 4];           \
            _Pragma("unroll")                                                    \
            for (int uu = 0; uu < 8; ++uu)                                       \
                y[uu] += a[uu].x * w4.x + a[uu].y * w4.y                         \
                       + a[uu].z * w4.z + a[uu].w * w4.w;                        \
        }                                                                        \
        _Pragma("unroll")                                                        \
        for (int uu = 0; uu < 8; ++uu) ybuf[(uu << 4) | wv][lane] = y[uu];       \
    }
    #define COMBINE(L)                                                           \
    {                                                                            \
        const float bias = blds[L][lane];                                        \
        _Pragma("unroll")                                                        \
        for (int uu = 0; uu < 8; ++uu) {                                         \
            const int u = (uu << 4) | wv;                                        \
            float acc = c_us[u][0] * XW[0][lane] + c_us[u][1] * XW[1][lane]      \
                      + c_us[u][2] * XW[2][lane] + c_us[u][3] * XW[3][lane]      \
                      + c_us[u][4] * XW[4][lane];                                \
            float val = (acc - occv[u] * y[uu]) * invv[u] + bias;                \
            xb0[u][lane] = fmaxf(val, 0.f);                                      \
        }                                                                        \
    }

    float y[8];
    // ======== P3: pmap+c_us | q | own-row gather + y-L0 (fused, no barrier) ====
    if (tid < NPOS) {
        int id = sl[tid];
        int pm = (id > 0) ? (int)idmap[id] : -1;
        pmap[tid] = pm;
        if (pm >= 0) atomicAdd(&c_us[pm][tid / MSONG], 1.f);
    }
    if (tid >= 128 && tid < 192) {
        int c = tid - 128;
        float acc = bias_q[c];
        #pragma unroll
        for (int e = 0; e < EMB; e++) acc += ctxv[e] * qw_l[e][c];
        qv[c] = acc;
    }
    #pragma unroll
    for (int g = 0; g < 2; ++g) {       // each wave gathers its OWN 8 rows
        const int uu = g * 4 + (lane >> 4);
        const int u  = (uu << 4) | wv;
        const int e4 = lane & 15;
        float4 v = make_float4(0.f, 0.f, 0.f, 0.f);
        if (u < U) v = ((const float4*)(song_emb + list_ids[u] * EMB))[e4];
        *(float4*)&xb0[u][e4 * 4] = v;
    }
    Y_COMPUTE(0)
    __syncthreads();   // B4

    // ======== P4: XWsum-L0 (waves 0-4) | occ/inv (waves 5-6) | k restage ======
    {
        float kr[4];
        #pragma unroll
        for (int j = 0; j < 4; j++) kr[j] = k_w[(eq0 * 4 + j) * EMB + col0];
        if (wv < NSHOW) {
            float acc = 0.f;
            #pragma unroll
            for (int i = 0; i < MSONG; i++) {
                int pm = pmap[wv * MSONG + i];
                if (pm >= 0) acc += ybuf[pm][lane];
            }
            XW[wv][lane] = acc;
        }
        if (tid >= 320 && tid < 448) {
            int u = tid - 320;
            float o = 0.f, r = 0.f;
            #pragma unroll
            for (int s = 0; s < NSHOW; s++) { float cc = c_us[u][s]; o += cc; r += cc * cntm1[s]; }
            occv[u] = o; invv[u] = 1.f / (r + 1e-10f);
        }
        *(float4*)&wldsT[0][col0][eq0 * 4] = make_float4(kr[0], kr[1], kr[2], kr[3]);  // wldsT[0] dead after y-L0
    }
    __syncthreads();   // B5

    // ======== P5: combine-L0 + y-L1 (fused, in-wave) | issue v load ==========
    float vr[4];
    #pragma unroll
    for (int j = 0; j < 4; j++) vr[j] = v_w[(eq0 * 4 + j) * EMB + col0];
    COMBINE(0)
    Y_COMPUTE(1)
    __syncthreads();   // B6

    // ======== P6: XWsum-L1 (waves 0-4) | v restage (wldsT[1] dead) ===========
    if (wv < NSHOW) {
        float acc = 0.f;
        #pragma unroll
        for (int i = 0; i < MSONG; i++) {
            int pm = pmap[wv * MSONG + i];
            if (pm >= 0) acc += ybuf[pm][lane];
        }
        XW[wv][lane] = acc;
    }
    *(float4*)&wldsT[1][col0][eq0 * 4] = make_float4(vr[0], vr[1], vr[2], vr[3]);
    __syncthreads();   // B7

    // ======== P7: combine-L1 | p1/p2 prefetch issue ==========================
    const int kk1 = tid >> 7, o1 = tid & 127;
    const int kk2 = tid >> 6, o2 = lane;
    float p1wr[24], p2wr[8];
    #pragma unroll
    for (int j = 0; j < 24; j++) p1wr[j] = p1_w[(kk1 * 24 + j) * 128 + o1];
    #pragma unroll
    for (int j = 0; j < 8; j++)  p2wr[j] = p2_w[(kk2 * 8 + j) * 64 + o2];
    COMBINE(1)
    __syncthreads();   // B8

    // ======== P8: show sums (waves 6-10) =====================================
    if (wv >= 6 && wv < 11) {
        int s = wv - 6;
        int pm[MSONG];
        #pragma unroll
        for (int i = 0; i < MSONG; i++) pm[i] = pmap[s * MSONG + i];
        float acc = 0.f;
        #pragma unroll
        for (int i = 0; i < MSONG; i++) if (pm[i] >= 0) acc += xb0[pm[i]][lane];
        Xsum[s][lane] = acc;
    }
    __syncthreads();   // B9

    // ======== P9: K·q -> raw scores (waves 0-4) | V (waves 5-9) ==============
    if (wv < NSHOW) {
        float s0 = 0.f;
        #pragma unroll 4
        for (int e4 = 0; e4 < 16; e4++) {
            const float4 w4 = *(const float4*)&wldsT[0][lane][e4 * 4];
            const float4 xs = *(const float4*)&Xsum[wv][e4 * 4];
            s0 += w4.x * xs.x + w4.y * xs.y + w4.z * xs.z + w4.w * xs.w;
        }
        float kk = s0 * invc[wv] + bias_k[lane];
        float p = kk * qv[lane];
        #pragma unroll
        for (int o = 32; o > 0; o >>= 1) p += __shfl_xor(p, o, 64);
        if (lane == 0) attnw[wv] = p * 0.125f;
    }
    if (wv >= 5 && wv < 10) {
        int s = wv - 5;
        float s0 = 0.f;
        #pragma unroll 4
        for (int e4 = 0; e4 < 16; e4++) {
            const float4 w4 = *(const float4*)&wldsT[1][lane][e4 * 4];
            const float4 xs = *(const float4*)&Xsum[s][e4 * 4];
            s0 += w4.x * xs.x + w4.y * xs.y + w4.z * xs.z + w4.w * xs.w;
        }
        vatt[s][lane] = s0 * invc[s] + bias_v[lane];
    }
    __syncthreads();   // B10

    // ======== P10: p1 partial with per-thread softmax (no softmax phase) =====
    {
        float a0 = attnw[0], a1 = attnw[1], a2 = attnw[2], a3 = attnw[3], a4 = attnw[4];
        float mx = fmaxf(fmaxf(fmaxf(a0, a1), fmaxf(a2, a3)), a4);
        float ex0 = expf(a0 - mx), ex1 = expf(a1 - mx), ex2 = expf(a2 - mx),
              ex3 = expf(a3 - mx), ex4 = expf(a4 - mx);
        float isum = 1.f / (ex0 + ex1 + ex2 + ex3 + ex4);
        const int uc = (int)idmap[sid];
        float acc = (kk1 == 0) ? bias_p1[o1] : 0.f;
        #pragma unroll
        for (int j = 0; j < 24; j++) {
            int e = kk1 * 24 + j;
            float h;
            if (e < 64)       h = xb0[uc][e];
            else if (e < 128) h = ctxv[e - 64];
            else {
                int d = e - 128;
                h = (ex0 * vatt[0][d] + ex1 * vatt[1][d] + ex2 * vatt[2][d]
                   + ex3 * vatt[3][d] + ex4 * vatt[4][d]) * isum;
            }
            acc += h * p1wr[j];
        }
        partial[tid] = acc;
    }
    __syncthreads();   // B11

    // ======== P11: p1 reduce ========
    if (tid < 128) {
        float acc = 0.f;
        #pragma unroll
        for (int kk = 0; kk < 8; kk++) acc += partial[kk * 128 + tid];
        h1b[tid] = fmaxf(acc, 0.f);
    }
    __syncthreads();   // B12

    // ======== P12: p2 partial (split-k 16) ========
    {
        float acc = (kk2 == 0) ? bias_p2[o2] : 0.f;
        #pragma unroll
        for (int j = 0; j < 8; j++) acc += h1b[kk2 * 8 + j] * p2wr[j];
        partial[tid] = acc;
    }
    __syncthreads();   // B13

    // ======== P13: wave0 p2 reduce + p3 + sigmoid ========
    if (wv == 0) {
        float acc = 0.f;
        #pragma unroll
        for (int kk = 0; kk < 16; kk++) acc += partial[kk * 64 + lane];
        float h2 = fmaxf(acc, 0.f);
        float p = h2 * bias_p3w[lane];
        #pragma unroll
        for (int o = 32; o > 0; o >>= 1) p += __shfl_xor(p, o, 64);
        if (lane == 0) out[b] = 1.f / (1.f + expf(-(p + bias_p3b)));
    }
}

extern "C" void kernel_launch(void* const* d_in, const int* in_sizes, int n_in,
                              void* d_out, int out_size, void* d_ws, size_t ws_size,
                              hipStream_t stream) {
    (void)n_in; (void)out_size; (void)d_ws; (void)ws_size;
    const int B = in_sizes[0];
    setsgnn_kernel<<<B, NT, 0, stream>>>(
        (const int*)d_in[0], (const int*)d_in[1], (const int*)d_in[2],
        (const int*)d_in[3], (const int*)d_in[4], (const int*)d_in[5],
        (const int*)d_in[6],
        (const float*)d_in[7],
        (const float*)d_in[8],  (const float*)d_in[9],
        (const float*)d_in[10], (const float*)d_in[11],
        (const float*)d_in[12], (const float*)d_in[13],
        (const float*)d_in[14], (const float*)d_in[15],
        (const float*)d_in[16], (const float*)d_in[17],
        (const float*)d_in[18], (const float*)d_in[19],
        (const float*)d_in[20], (const float*)d_in[21],
        (const float*)d_in[22],
        (const float*)d_in[23], (const float*)d_in[24],
        (const float*)d_in[25], (const float*)d_in[26],
        (const float*)d_in[27], (const float*)d_in[28],
        (const float*)d_in[29], (const float*)d_in[30],
        (float*)d_out);
}